// Round 1
// baseline (131.432 us; speedup 1.0000x reference)
//
#include <hip/hip_runtime.h>
#include <hip/hip_bf16.h>
#include <math.h>

#define HD 256
#define BB 64
#define DD 2048

typedef __attribute__((ext_vector_type(8))) short  short8;
typedef __attribute__((ext_vector_type(4))) float  float4v;
typedef __attribute__((ext_vector_type(4))) unsigned short ushort4v;

__device__ inline unsigned short f2bf(float f) {
    unsigned u = __builtin_bit_cast(unsigned, f);
    u += 0x7FFFu + ((u >> 16) & 1u);   // RNE
    return (unsigned short)(u >> 16);
}

// ---------------- kernel 0: W1 f32 -> bf16 ----------------
__global__ __launch_bounds__(256) void k_cvt_w1(const float* __restrict__ W1,
                                                unsigned short* __restrict__ w1b) {
    int i = blockIdx.x * 256 + threadIdx.x;          // 16384 float4s
    float4v v = ((const float4v*)W1)[i];
    ushort4v o;
    o[0] = f2bf(v[0]); o[1] = f2bf(v[1]); o[2] = f2bf(v[2]); o[3] = f2bf(v[3]);
    ((ushort4v*)w1b)[i] = o;
}

// ---------------- kernel 1: g23[b,h] = ctx.W2^T + b2 + hid.W3^T ----------------
__global__ __launch_bounds__(256) void k_g23(const float* __restrict__ ctx,
                                             const float* __restrict__ hid,
                                             const float* __restrict__ W2,
                                             const float* __restrict__ b2,
                                             const float* __restrict__ W3,
                                             float* __restrict__ g23) {
    int b = blockIdx.x, t = threadIdx.x;
    __shared__ float c[HD], hh[HD];
    c[t]  = ctx[b * HD + t];
    hh[t] = hid[b * HD + t];
    __syncthreads();
    const float4v* w2 = (const float4v*)(W2 + (size_t)t * HD);
    const float4v* w3 = (const float4v*)(W3 + (size_t)t * HD);
    float acc = b2[t];
    #pragma unroll 8
    for (int k = 0; k < 64; ++k) {
        float4v a = w2[k], d = w3[k];
        int k4 = k * 4;
        acc += c[k4] * a[0] + c[k4 + 1] * a[1] + c[k4 + 2] * a[2] + c[k4 + 3] * a[3];
        acc += hh[k4] * d[0] + hh[k4 + 1] * d[1] + hh[k4 + 2] * d[2] + hh[k4 + 3] * d[3];
    }
    g23[b * HD + t] = acc;
}

// ---------------- kernel 2 (main): scores[b,d] = W4 . tanh(g1 + g23) ----------------
// block = 256 thr (4 waves), handles one batch b and 64 d-rows.
// wave w computes all 64 rows x h-cols [w*64, w*64+64).
__global__ __launch_bounds__(256) void k_scores(const float* __restrict__ q,
                                                const unsigned short* __restrict__ w1b,
                                                const float* __restrict__ g23,
                                                const float* __restrict__ W4,
                                                float* __restrict__ scores) {
    __shared__ unsigned short qs[64 * HD];   // bf16 tile, XOR-swizzled rows
    __shared__ float sp[4 * 64];

    const int t = threadIdx.x;
    const int b = blockIdx.y;
    const int d0 = blockIdx.x * 64;
    const int lane = t & 63, wave = t >> 6;
    const int l15 = lane & 15, lk = lane >> 4;

    // ---- stage question tile (64 x 256 f32 -> bf16 LDS) ----
    const float* qbase = q + ((size_t)(b * DD + d0)) * HD;
    #pragma unroll
    for (int i = 0; i < 8; ++i) {
        int chunk = t + i * 256;          // 2048 chunks of 8 elems
        int r  = chunk >> 5;              // 32 chunks per row
        int k0 = (chunk & 31) * 8;
        float4v v0 = *(const float4v*)(qbase + r * HD + k0);
        float4v v1 = *(const float4v*)(qbase + r * HD + k0 + 4);
        short8 p;
        p[0] = (short)f2bf(v0[0]); p[1] = (short)f2bf(v0[1]);
        p[2] = (short)f2bf(v0[2]); p[3] = (short)f2bf(v0[3]);
        p[4] = (short)f2bf(v1[0]); p[5] = (short)f2bf(v1[1]);
        p[6] = (short)f2bf(v1[2]); p[7] = (short)f2bf(v1[3]);
        *(short8*)&qs[r * HD + (k0 ^ ((r & 7) << 3))] = p;
    }
    __syncthreads();

    const int hbase = wave * 64;
    float g23v[4], w4v[4];
    #pragma unroll
    for (int nf = 0; nf < 4; ++nf) {
        int h = hbase + nf * 16 + l15;
        g23v[nf] = g23[b * HD + h];
        w4v[nf]  = W4[h];
    }

    float4v acc[4][4];
    #pragma unroll
    for (int mf = 0; mf < 4; ++mf)
        #pragma unroll
        for (int nf = 0; nf < 4; ++nf)
            acc[mf][nf] = (float4v){0.f, 0.f, 0.f, 0.f};

    #pragma unroll
    for (int kb = 0; kb < 8; ++kb) {
        const int c0 = kb * 32 + lk * 8;
        short8 af[4];
        #pragma unroll
        for (int mf = 0; mf < 4; ++mf) {
            int r = mf * 16 + l15;
            af[mf] = *(const short8*)&qs[r * HD + (c0 ^ ((r & 7) << 3))];
        }
        #pragma unroll
        for (int nf = 0; nf < 4; ++nf) {
            short8 bf = *(const short8*)&w1b[(size_t)(hbase + nf * 16 + l15) * HD + c0];
            #pragma unroll
            for (int mf = 0; mf < 4; ++mf)
                acc[mf][nf] = __builtin_amdgcn_mfma_f32_16x16x32_bf16(af[mf], bf, acc[mf][nf], 0, 0, 0);
        }
    }

    // ---- epilogue: tanh + dot with W4 ----
    float ps[4][4];
    #pragma unroll
    for (int mf = 0; mf < 4; ++mf)
        #pragma unroll
        for (int r = 0; r < 4; ++r) ps[mf][r] = 0.f;

    #pragma unroll
    for (int nf = 0; nf < 4; ++nf) {
        float g = g23v[nf], w = w4v[nf];
        #pragma unroll
        for (int mf = 0; mf < 4; ++mf)
            #pragma unroll
            for (int r = 0; r < 4; ++r)
                ps[mf][r] += tanhf(acc[mf][nf][r] + g) * w;
    }

    // reduce across the 16 col-lanes (rows are indexed by lk*4+r, same for all l15)
    #pragma unroll
    for (int mf = 0; mf < 4; ++mf)
        #pragma unroll
        for (int r = 0; r < 4; ++r) {
            float v = ps[mf][r];
            v += __shfl_xor(v, 1, 16);
            v += __shfl_xor(v, 2, 16);
            v += __shfl_xor(v, 4, 16);
            v += __shfl_xor(v, 8, 16);
            ps[mf][r] = v;
        }
    if (l15 == 0) {
        #pragma unroll
        for (int mf = 0; mf < 4; ++mf)
            #pragma unroll
            for (int r = 0; r < 4; ++r)
                sp[wave * 64 + mf * 16 + lk * 4 + r] = ps[mf][r];
    }
    __syncthreads();
    if (t < 64) {
        float s = sp[t] + sp[64 + t] + sp[128 + t] + sp[192 + t];
        scores[b * DD + d0 + t] = s;   // b4 dropped: softmax shift-invariant
    }
}

// ---------------- kernel 3: per-batch softmax stats ----------------
__global__ __launch_bounds__(256) void k_stats(const float* __restrict__ scores,
                                               float* __restrict__ stats) {
    int b = blockIdx.x, t = threadIdx.x;
    __shared__ float red[256];
    float sv[8];
    float lm = -1e30f;
    #pragma unroll
    for (int i = 0; i < 8; ++i) {
        sv[i] = scores[b * DD + t + i * 256];
        lm = fmaxf(lm, sv[i]);
    }
    red[t] = lm; __syncthreads();
    for (int s = 128; s > 0; s >>= 1) {
        if (t < s) red[t] = fmaxf(red[t], red[t + s]);
        __syncthreads();
    }
    float mx = red[0];
    __syncthreads();
    float ls = 0.f;
    #pragma unroll
    for (int i = 0; i < 8; ++i) ls += expf(sv[i] - mx);
    red[t] = ls; __syncthreads();
    for (int s = 128; s > 0; s >>= 1) {
        if (t < s) red[t] += red[t + s];
        __syncthreads();
    }
    if (t == 0) { stats[b * 2] = mx; stats[b * 2 + 1] = 1.f / red[0]; }
}

// ---------------- kernel 4: partial weighted sums ----------------
__global__ __launch_bounds__(256) void k_pout(const float* __restrict__ q,
                                              const float* __restrict__ scores,
                                              const float* __restrict__ stats,
                                              float* __restrict__ part) {
    const int b = blockIdx.y, ch = blockIdx.x, t = threadIdx.x;
    __shared__ float wl[256];
    const float mx = stats[b * 2], inv = stats[b * 2 + 1];
    const int d0 = ch * 256;
    wl[t] = expf(scores[b * DD + d0 + t] - mx) * inv;
    __syncthreads();
    const float* qb = q + ((size_t)(b * DD + d0)) * HD + t;
    float acc = 0.f;
    #pragma unroll 4
    for (int d = 0; d < 256; ++d) acc += wl[d] * qb[(size_t)d * HD];
    part[(size_t)(b * 8 + ch) * HD + t] = acc;
}

// ---------------- kernel 5: reduce partials ----------------
__global__ __launch_bounds__(256) void k_rout(const float* __restrict__ part,
                                              float* __restrict__ out) {
    int b = blockIdx.x, t = threadIdx.x;
    float s = 0.f;
    #pragma unroll
    for (int c = 0; c < 8; ++c) s += part[(size_t)(b * 8 + c) * HD + t];
    out[b * HD + t] = s;
}

extern "C" void kernel_launch(void* const* d_in, const int* in_sizes, int n_in,
                              void* d_out, int out_size, void* d_ws, size_t ws_size,
                              hipStream_t stream) {
    (void)in_sizes; (void)n_in; (void)out_size; (void)ws_size;
    const float* ctx = (const float*)d_in[0];
    const float* q   = (const float*)d_in[1];
    const float* hid = (const float*)d_in[2];
    const float* W1  = (const float*)d_in[3];
    const float* W2  = (const float*)d_in[4];
    const float* b2  = (const float*)d_in[5];
    const float* W3  = (const float*)d_in[6];
    const float* W4  = (const float*)d_in[7];
    // d_in[8] = b4: dropped (softmax shift-invariant)
    float* out = (float*)d_out;

    char* ws = (char*)d_ws;
    unsigned short* w1b = (unsigned short*)(ws);            // 131072 B
    float* g23    = (float*)(ws + 131072);                  //  65536 B
    float* scores = (float*)(ws + 196608);                  // 524288 B
    float* stats  = (float*)(ws + 720896);                  //    512 B
    float* part   = (float*)(ws + 721408);                  // 524288 B

    k_cvt_w1<<<dim3(64), dim3(256), 0, stream>>>(W1, w1b);
    k_g23  <<<dim3(BB), dim3(256), 0, stream>>>(ctx, hid, W2, b2, W3, g23);
    k_scores<<<dim3(DD / 64, BB), dim3(256), 0, stream>>>(q, w1b, g23, W4, scores);
    k_stats<<<dim3(BB), dim3(256), 0, stream>>>(scores, stats);
    k_pout <<<dim3(8, BB), dim3(256), 0, stream>>>(q, scores, stats, part);
    k_rout <<<dim3(BB), dim3(256), 0, stream>>>(part, out);
}

// Round 2
// 124.349 us; speedup vs baseline: 1.0570x; 1.0570x over previous
//
#include <hip/hip_runtime.h>
#include <hip/hip_bf16.h>
#include <math.h>

#define HD 256
#define BB 64
#define DD 2048

typedef __attribute__((ext_vector_type(8))) short  short8;
typedef __attribute__((ext_vector_type(4))) float  float4v;
typedef __attribute__((ext_vector_type(4))) unsigned short ushort4v;

__device__ inline unsigned short f2bf(float f) {
    unsigned u = __builtin_bit_cast(unsigned, f);
    u += 0x7FFFu + ((u >> 16) & 1u);   // RNE
    return (unsigned short)(u >> 16);
}

__device__ inline float fast_exp2(float x) {
    float r;
    asm("v_exp_f32 %0, %1" : "=v"(r) : "v"(x));
    return r;
}
__device__ inline float fast_expf(float x) {
    return fast_exp2(x * 1.4426950408889634f);
}
__device__ inline float fast_tanh(float x) {
    // tanh(x) = (e^{2x}-1)/(e^{2x}+1); y = 2x*log2(e) clamped so exp2 never overflows
    float y = x * 2.8853900817779268f;
    y = fminf(fmaxf(y, -30.f), 30.f);
    float t = fast_exp2(y);
    float r;
    asm("v_rcp_f32 %0, %1" : "=v"(r) : "v"(t + 1.f));
    return (t - 1.f) * r;
}

// ---------------- kernel 0 (fused): W1 f32->bf16  AND  g23 = ctx.W2^T + b2 + hid.W3^T ----
__global__ __launch_bounds__(256) void k_prep(const float* __restrict__ W1,
                                              unsigned short* __restrict__ w1b,
                                              const float* __restrict__ ctx,
                                              const float* __restrict__ hid,
                                              const float* __restrict__ W2,
                                              const float* __restrict__ b2,
                                              const float* __restrict__ W3,
                                              float* __restrict__ g23) {
    if (blockIdx.x < 64) {
        int i = blockIdx.x * 256 + threadIdx.x;          // 16384 float4s
        float4v v = ((const float4v*)W1)[i];
        ushort4v o;
        o[0] = f2bf(v[0]); o[1] = f2bf(v[1]); o[2] = f2bf(v[2]); o[3] = f2bf(v[3]);
        ((ushort4v*)w1b)[i] = o;
    } else {
        int b = blockIdx.x - 64, t = threadIdx.x;
        __shared__ float c[HD], hh[HD];
        c[t]  = ctx[b * HD + t];
        hh[t] = hid[b * HD + t];
        __syncthreads();
        const float4v* w2 = (const float4v*)(W2 + (size_t)t * HD);
        const float4v* w3 = (const float4v*)(W3 + (size_t)t * HD);
        float acc = b2[t];
        #pragma unroll 8
        for (int k = 0; k < 64; ++k) {
            float4v a = w2[k], d = w3[k];
            int k4 = k * 4;
            acc += c[k4] * a[0] + c[k4 + 1] * a[1] + c[k4 + 2] * a[2] + c[k4 + 3] * a[3];
            acc += hh[k4] * d[0] + hh[k4 + 1] * d[1] + hh[k4 + 2] * d[2] + hh[k4 + 3] * d[3];
        }
        g23[b * HD + t] = acc;
    }
}

// ---------------- kernel 1 (main): scores[b,d] = W4 . tanh(g1 + g23) ----------------
// block = 256 thr (4 waves); persistent over 4 tiles of 64 d-rows; LDS double-buffered;
// loads for tile t+1 issued one full MFMA phase ahead.
__global__ __launch_bounds__(256, 2) void k_scores(const float* __restrict__ q,
                                                   const unsigned short* __restrict__ w1b,
                                                   const float* __restrict__ g23,
                                                   const float* __restrict__ W4,
                                                   float* __restrict__ scores) {
    __shared__ unsigned short qs[2][64 * HD];   // bf16 tiles, XOR-swizzled rows
    __shared__ float sp[4 * 64];

    const int t = threadIdx.x;
    const int b = blockIdx.y;
    const int dbase = blockIdx.x * 256;         // this block: rows [dbase, dbase+256)
    const int lane = t & 63, wave = t >> 6;
    const int l15 = lane & 15, lk = lane >> 4;

    const float* qb0 = q + ((size_t)(b * DD + dbase)) * HD;

    // per-thread staging geometry (fixed): chunk = t + i*256, 8 floats each
    float4v st[16];

    // ---- prologue: load tile 0, write buf0, issue loads for tile 1 ----
    #pragma unroll
    for (int i = 0; i < 8; ++i) {
        int chunk = t + i * 256;
        int r = chunk >> 5, k0 = (chunk & 31) * 8;
        st[2 * i]     = *(const float4v*)(qb0 + r * HD + k0);
        st[2 * i + 1] = *(const float4v*)(qb0 + r * HD + k0 + 4);
    }
    #pragma unroll
    for (int i = 0; i < 8; ++i) {
        int chunk = t + i * 256;
        int r = chunk >> 5, k0 = (chunk & 31) * 8;
        short8 p;
        p[0] = (short)f2bf(st[2*i][0]);   p[1] = (short)f2bf(st[2*i][1]);
        p[2] = (short)f2bf(st[2*i][2]);   p[3] = (short)f2bf(st[2*i][3]);
        p[4] = (short)f2bf(st[2*i+1][0]); p[5] = (short)f2bf(st[2*i+1][1]);
        p[6] = (short)f2bf(st[2*i+1][2]); p[7] = (short)f2bf(st[2*i+1][3]);
        *(short8*)&qs[0][r * HD + (k0 ^ ((r & 7) << 3))] = p;
    }
    #pragma unroll
    for (int i = 0; i < 8; ++i) {
        int chunk = t + i * 256;
        int r = chunk >> 5, k0 = (chunk & 31) * 8;
        st[2 * i]     = *(const float4v*)(qb0 + (64 + r) * HD + k0);
        st[2 * i + 1] = *(const float4v*)(qb0 + (64 + r) * HD + k0 + 4);
    }

    // invariants
    const int hbase = wave * 64;
    float g23v[4], w4v[4];
    #pragma unroll
    for (int nf = 0; nf < 4; ++nf) {
        int h = hbase + nf * 16 + l15;
        g23v[nf] = g23[b * HD + h];
        w4v[nf]  = W4[h];
    }

    int cur = 0;
    for (int tt = 0; tt < 4; ++tt) {
        __syncthreads();                         // buf[cur] ready, buf[cur^1] free
        const unsigned short* bufc = qs[cur];

        float4v acc[4][4];
        #pragma unroll
        for (int mf = 0; mf < 4; ++mf)
            #pragma unroll
            for (int nf = 0; nf < 4; ++nf)
                acc[mf][nf] = (float4v){0.f, 0.f, 0.f, 0.f};

        #pragma unroll
        for (int kb = 0; kb < 8; ++kb) {
            const int c0 = kb * 32 + lk * 8;
            short8 af[4];
            #pragma unroll
            for (int mf = 0; mf < 4; ++mf) {
                int r = mf * 16 + l15;
                af[mf] = *(const short8*)&bufc[r * HD + (c0 ^ ((r & 7) << 3))];
            }
            #pragma unroll
            for (int nf = 0; nf < 4; ++nf) {
                short8 bf = *(const short8*)&w1b[(size_t)(hbase + nf * 16 + l15) * HD + c0];
                #pragma unroll
                for (int mf = 0; mf < 4; ++mf)
                    acc[mf][nf] = __builtin_amdgcn_mfma_f32_16x16x32_bf16(af[mf], bf, acc[mf][nf], 0, 0, 0);
            }
        }

        // ---- epilogue: fast tanh + dot with W4 ----
        float ps[4][4];
        #pragma unroll
        for (int mf = 0; mf < 4; ++mf)
            #pragma unroll
            for (int r = 0; r < 4; ++r) ps[mf][r] = 0.f;

        #pragma unroll
        for (int nf = 0; nf < 4; ++nf) {
            float g = g23v[nf], w = w4v[nf];
            #pragma unroll
            for (int mf = 0; mf < 4; ++mf)
                #pragma unroll
                for (int r = 0; r < 4; ++r)
                    ps[mf][r] += fast_tanh(acc[mf][nf][r] + g) * w;
        }

        #pragma unroll
        for (int mf = 0; mf < 4; ++mf)
            #pragma unroll
            for (int r = 0; r < 4; ++r) {
                float v = ps[mf][r];
                v += __shfl_xor(v, 1, 16);
                v += __shfl_xor(v, 2, 16);
                v += __shfl_xor(v, 4, 16);
                v += __shfl_xor(v, 8, 16);
                ps[mf][r] = v;
            }
        if (l15 == 0) {
            #pragma unroll
            for (int mf = 0; mf < 4; ++mf)
                #pragma unroll
                for (int r = 0; r < 4; ++r)
                    sp[wave * 64 + mf * 16 + lk * 4 + r] = ps[mf][r];
        }

        // ---- stage tile tt+1 into buf[cur^1]; issue loads for tile tt+2 ----
        if (tt < 3) {
            #pragma unroll
            for (int i = 0; i < 8; ++i) {
                int chunk = t + i * 256;
                int r = chunk >> 5, k0 = (chunk & 31) * 8;
                short8 p;
                p[0] = (short)f2bf(st[2*i][0]);   p[1] = (short)f2bf(st[2*i][1]);
                p[2] = (short)f2bf(st[2*i][2]);   p[3] = (short)f2bf(st[2*i][3]);
                p[4] = (short)f2bf(st[2*i+1][0]); p[5] = (short)f2bf(st[2*i+1][1]);
                p[6] = (short)f2bf(st[2*i+1][2]); p[7] = (short)f2bf(st[2*i+1][3]);
                *(short8*)&qs[cur ^ 1][r * HD + (k0 ^ ((r & 7) << 3))] = p;
            }
            if (tt < 2) {
                const float* qbn = qb0 + (size_t)(tt + 2) * 64 * HD;
                #pragma unroll
                for (int i = 0; i < 8; ++i) {
                    int chunk = t + i * 256;
                    int r = chunk >> 5, k0 = (chunk & 31) * 8;
                    st[2 * i]     = *(const float4v*)(qbn + r * HD + k0);
                    st[2 * i + 1] = *(const float4v*)(qbn + r * HD + k0 + 4);
                }
            }
        }

        __syncthreads();                         // sp visible; buf[cur^1] written
        if (t < 64) {
            float s = sp[t] + sp[64 + t] + sp[128 + t] + sp[192 + t];
            scores[b * DD + dbase + tt * 64 + t] = s;   // b4 dropped: softmax shift-invariant
        }
        cur ^= 1;
    }
}

// ---------------- kernel 2: per-batch softmax stats ----------------
__global__ __launch_bounds__(256) void k_stats(const float* __restrict__ scores,
                                               float* __restrict__ stats) {
    int b = blockIdx.x, t = threadIdx.x;
    __shared__ float red[256];
    float sv[8];
    float lm = -1e30f;
    #pragma unroll
    for (int i = 0; i < 8; ++i) {
        sv[i] = scores[b * DD + t + i * 256];
        lm = fmaxf(lm, sv[i]);
    }
    red[t] = lm; __syncthreads();
    for (int s = 128; s > 0; s >>= 1) {
        if (t < s) red[t] = fmaxf(red[t], red[t + s]);
        __syncthreads();
    }
    float mx = red[0];
    __syncthreads();
    float ls = 0.f;
    #pragma unroll
    for (int i = 0; i < 8; ++i) ls += fast_expf(sv[i] - mx);
    red[t] = ls; __syncthreads();
    for (int s = 128; s > 0; s >>= 1) {
        if (t < s) red[t] += red[t + s];
        __syncthreads();
    }
    if (t == 0) { stats[b * 2] = mx; stats[b * 2 + 1] = 1.f / red[0]; }
}

// ---------------- kernel 3: partial weighted sums ----------------
__global__ __launch_bounds__(256) void k_pout(const float* __restrict__ q,
                                              const float* __restrict__ scores,
                                              const float* __restrict__ stats,
                                              float* __restrict__ part) {
    const int b = blockIdx.y, ch = blockIdx.x, t = threadIdx.x;
    __shared__ float wl[256];
    const float mx = stats[b * 2], inv = stats[b * 2 + 1];
    const int d0 = ch * 256;
    wl[t] = fast_expf(scores[b * DD + d0 + t] - mx) * inv;
    __syncthreads();
    const float* qb = q + ((size_t)(b * DD + d0)) * HD + t;
    float a0 = 0.f, a1 = 0.f, a2 = 0.f, a3 = 0.f;
    #pragma unroll 8
    for (int d = 0; d < 256; d += 4) {
        a0 += wl[d]     * qb[(size_t)d * HD];
        a1 += wl[d + 1] * qb[(size_t)(d + 1) * HD];
        a2 += wl[d + 2] * qb[(size_t)(d + 2) * HD];
        a3 += wl[d + 3] * qb[(size_t)(d + 3) * HD];
    }
    part[(size_t)(b * 8 + ch) * HD + t] = (a0 + a1) + (a2 + a3);
}

// ---------------- kernel 4: reduce partials ----------------
__global__ __launch_bounds__(256) void k_rout(const float* __restrict__ part,
                                              float* __restrict__ out) {
    int b = blockIdx.x, t = threadIdx.x;
    float s = 0.f;
    #pragma unroll
    for (int c = 0; c < 8; ++c) s += part[(size_t)(b * 8 + c) * HD + t];
    out[b * HD + t] = s;
}

extern "C" void kernel_launch(void* const* d_in, const int* in_sizes, int n_in,
                              void* d_out, int out_size, void* d_ws, size_t ws_size,
                              hipStream_t stream) {
    (void)in_sizes; (void)n_in; (void)out_size; (void)ws_size;
    const float* ctx = (const float*)d_in[0];
    const float* q   = (const float*)d_in[1];
    const float* hid = (const float*)d_in[2];
    const float* W1  = (const float*)d_in[3];
    const float* W2  = (const float*)d_in[4];
    const float* b2  = (const float*)d_in[5];
    const float* W3  = (const float*)d_in[6];
    const float* W4  = (const float*)d_in[7];
    // d_in[8] = b4: dropped (softmax shift-invariant)
    float* out = (float*)d_out;

    char* ws = (char*)d_ws;
    unsigned short* w1b = (unsigned short*)(ws);            // 131072 B
    float* g23    = (float*)(ws + 131072);                  //  65536 B
    float* scores = (float*)(ws + 196608);                  // 524288 B
    float* stats  = (float*)(ws + 720896);                  //    512 B
    float* part   = (float*)(ws + 721408);                  // 524288 B

    k_prep <<<dim3(128), dim3(256), 0, stream>>>(W1, w1b, ctx, hid, W2, b2, W3, g23);
    k_scores<<<dim3(DD / 256, BB), dim3(256), 0, stream>>>(q, w1b, g23, W4, scores);
    k_stats<<<dim3(BB), dim3(256), 0, stream>>>(scores, stats);
    k_pout <<<dim3(8, BB), dim3(256), 0, stream>>>(q, scores, stats, part);
    k_rout <<<dim3(BB), dim3(256), 0, stream>>>(part, out);
}

// Round 3
// 121.876 us; speedup vs baseline: 1.0784x; 1.0203x over previous
//
#include <hip/hip_runtime.h>
#include <hip/hip_bf16.h>
#include <math.h>

#define HD 256
#define BB 64
#define DD 2048

// padded LDS row: 276 f32 words (1104 B). 276 mod 32 = 20 -> fragment-row
// reads spread across 8 bank offsets -> 2-way conflict (free, m136).
#define ROWW 276
#define CHPR 69          // 16B chunks per padded row (69*16 = 1104)
#define NCH  35          // ceil(32*69/64) wave-chunks of 1024 B

typedef __attribute__((ext_vector_type(8))) short  short8;
typedef __attribute__((ext_vector_type(4))) float  float4v;
typedef __attribute__((ext_vector_type(4))) unsigned short ushort4v;

__device__ inline unsigned short f2bf(float f) {
    unsigned u = __builtin_bit_cast(unsigned, f);
    u += 0x7FFFu + ((u >> 16) & 1u);   // RNE
    return (unsigned short)(u >> 16);
}

__device__ inline float fast_exp2(float x) {
    float r;
    asm("v_exp_f32 %0, %1" : "=v"(r) : "v"(x));
    return r;
}
__device__ inline float fast_expf(float x) { return fast_exp2(x * 1.4426950408889634f); }
__device__ inline float fast_tanh(float x) {
    float y = x * 2.8853900817779268f;          // 2x * log2(e)
    y = fminf(fmaxf(y, -30.f), 30.f);
    float t = fast_exp2(y);
    float r;
    asm("v_rcp_f32 %0, %1" : "=v"(r) : "v"(t + 1.f));
    return (t - 1.f) * r;
}

__device__ inline void load_lds16(const void* g, void* l) {
    __builtin_amdgcn_global_load_lds(
        (const __attribute__((address_space(1))) void*)g,
        (__attribute__((address_space(3))) void*)l, 16, 0, 0);
}

// ---------------- kernel 0 (fused): W1 f32->bf16  AND  g23 = ctx.W2^T + b2 + hid.W3^T ----
__global__ __launch_bounds__(256) void k_prep(const float* __restrict__ W1,
                                              unsigned short* __restrict__ w1b,
                                              const float* __restrict__ ctx,
                                              const float* __restrict__ hid,
                                              const float* __restrict__ W2,
                                              const float* __restrict__ b2,
                                              const float* __restrict__ W3,
                                              float* __restrict__ g23) {
    if (blockIdx.x < 64) {
        int i = blockIdx.x * 256 + threadIdx.x;          // 16384 float4s
        float4v v = ((const float4v*)W1)[i];
        ushort4v o;
        o[0] = f2bf(v[0]); o[1] = f2bf(v[1]); o[2] = f2bf(v[2]); o[3] = f2bf(v[3]);
        ((ushort4v*)w1b)[i] = o;
    } else {
        int b = blockIdx.x - 64, t = threadIdx.x;
        __shared__ float c[HD], hh[HD];
        c[t]  = ctx[b * HD + t];
        hh[t] = hid[b * HD + t];
        __syncthreads();
        const float4v* w2 = (const float4v*)(W2 + (size_t)t * HD);
        const float4v* w3 = (const float4v*)(W3 + (size_t)t * HD);
        float acc = b2[t];
        #pragma unroll 8
        for (int k = 0; k < 64; ++k) {
            float4v a = w2[k], d = w3[k];
            int k4 = k * 4;
            acc += c[k4] * a[0] + c[k4 + 1] * a[1] + c[k4 + 2] * a[2] + c[k4 + 3] * a[3];
            acc += hh[k4] * d[0] + hh[k4 + 1] * d[1] + hh[k4 + 2] * d[2] + hh[k4 + 3] * d[3];
        }
        g23[b * HD + t] = acc;
    }
}

// ---------------- kernel 1 (main): scores[b,d] = W4 . tanh(q@W1^T + g23) --------------
// grid (64, 64): one 32-row d-tile per block; 4 waves, wave owns 64 h-cols.
// q staged f32 -> LDS via global_load_lds (width 16), padded rows kill conflicts.
__global__ __launch_bounds__(256) void k_scores(const float* __restrict__ q,
                                                const unsigned short* __restrict__ w1b,
                                                const float* __restrict__ g23,
                                                const float* __restrict__ W4,
                                                float* __restrict__ scores) {
    __shared__ __attribute__((aligned(16))) float qs[NCH * 256];  // 35840 B
    __shared__ float sp[4 * 32];

    const int t = threadIdx.x;
    const int b = blockIdx.y;
    const int d0 = blockIdx.x * 32;
    const int lane = t & 63, wave = t >> 6;
    const int l15 = lane & 15, lk = lane >> 4;

    // ---- stage: 35 chunks of 1024 B, 9 per wave (last skipped) ----
    const char* gtile = (const char*)(q + ((size_t)(b * DD + d0)) * HD);
    #pragma unroll
    for (int i = 0; i < 9; ++i) {
        int j = wave * 9 + i;
        if (j < NCH) {
            int x  = j * 64 + lane;            // 16B-chunk index in padded tile
            int r  = x / CHPR;                 // compiler magic-div
            int cb = x - r * CHPR;
            int rr = (r < 32) ? r : 0;         // pad lanes -> dummy (in-bounds) addr
            int cc = (cb < 64) ? cb : 0;
            load_lds16(gtile + (size_t)rr * 1024 + cc * 16,
                       (char*)qs + j * 1024);
        }
    }

    const int hbase = wave * 64;
    float g23v[4], w4v[4];
    #pragma unroll
    for (int nf = 0; nf < 4; ++nf) {
        int h = hbase + nf * 16 + l15;
        g23v[nf] = g23[b * HD + h];
        w4v[nf]  = W4[h];
    }

    __syncthreads();   // compiler drains vmcnt(0) here -> LDS tile ready

    float4v acc[2][4];
    #pragma unroll
    for (int mf = 0; mf < 2; ++mf)
        #pragma unroll
        for (int nf = 0; nf < 4; ++nf)
            acc[mf][nf] = (float4v){0.f, 0.f, 0.f, 0.f};

    #pragma unroll
    for (int kb = 0; kb < 8; ++kb) {
        const int c0 = kb * 32 + lk * 8;
        short8 af[2];
        #pragma unroll
        for (int mf = 0; mf < 2; ++mf) {
            const float* p = &qs[(mf * 16 + l15) * ROWW + c0];
            float4v lo = *(const float4v*)p;
            float4v hi = *(const float4v*)(p + 4);
            short8 a;
            a[0] = (short)f2bf(lo[0]); a[1] = (short)f2bf(lo[1]);
            a[2] = (short)f2bf(lo[2]); a[3] = (short)f2bf(lo[3]);
            a[4] = (short)f2bf(hi[0]); a[5] = (short)f2bf(hi[1]);
            a[6] = (short)f2bf(hi[2]); a[7] = (short)f2bf(hi[3]);
            af[mf] = a;
        }
        #pragma unroll
        for (int nf = 0; nf < 4; ++nf) {
            short8 bf = *(const short8*)&w1b[(size_t)(hbase + nf * 16 + l15) * HD + c0];
            acc[0][nf] = __builtin_amdgcn_mfma_f32_16x16x32_bf16(af[0], bf, acc[0][nf], 0, 0, 0);
            acc[1][nf] = __builtin_amdgcn_mfma_f32_16x16x32_bf16(af[1], bf, acc[1][nf], 0, 0, 0);
        }
    }

    // ---- epilogue: tanh + dot W4, reduce over h ----
    #pragma unroll
    for (int mf = 0; mf < 2; ++mf)
        #pragma unroll
        for (int r = 0; r < 4; ++r) {
            float s = 0.f;
            #pragma unroll
            for (int nf = 0; nf < 4; ++nf)
                s += fast_tanh(acc[mf][nf][r] + g23v[nf]) * w4v[nf];
            s += __shfl_xor(s, 1, 16);
            s += __shfl_xor(s, 2, 16);
            s += __shfl_xor(s, 4, 16);
            s += __shfl_xor(s, 8, 16);
            if (l15 == 0) sp[wave * 32 + mf * 16 + lk * 4 + r] = s;
        }
    __syncthreads();
    if (t < 32) {
        float s = sp[t] + sp[32 + t] + sp[64 + t] + sp[96 + t];
        scores[b * DD + d0 + t] = s;   // b4 dropped: softmax shift-invariant
    }
}

// ---------------- kernel 2: per-batch softmax stats ----------------
__global__ __launch_bounds__(256) void k_stats(const float* __restrict__ scores,
                                               float* __restrict__ stats) {
    int b = blockIdx.x, t = threadIdx.x;
    __shared__ float red[256];
    float sv[8];
    float lm = -1e30f;
    #pragma unroll
    for (int i = 0; i < 8; ++i) {
        sv[i] = scores[b * DD + t + i * 256];
        lm = fmaxf(lm, sv[i]);
    }
    red[t] = lm; __syncthreads();
    for (int s = 128; s > 0; s >>= 1) {
        if (t < s) red[t] = fmaxf(red[t], red[t + s]);
        __syncthreads();
    }
    float mx = red[0];
    __syncthreads();
    float ls = 0.f;
    #pragma unroll
    for (int i = 0; i < 8; ++i) ls += fast_expf(sv[i] - mx);
    red[t] = ls; __syncthreads();
    for (int s = 128; s > 0; s >>= 1) {
        if (t < s) red[t] += red[t + s];
        __syncthreads();
    }
    if (t == 0) { stats[b * 2] = mx; stats[b * 2 + 1] = 1.f / red[0]; }
}

// ---------------- kernel 3: partial weighted sums (float4 lanes) ----------------
__global__ __launch_bounds__(256) void k_pout(const float* __restrict__ q,
                                              const float* __restrict__ scores,
                                              const float* __restrict__ stats,
                                              float* __restrict__ part) {
    const int b = blockIdx.y, ch = blockIdx.x, t = threadIdx.x;
    __shared__ float wl[256];
    __shared__ float4v red[256];
    const float mx = stats[b * 2], inv = stats[b * 2 + 1];
    const int d0 = ch * 256;
    wl[t] = fast_expf(scores[b * DD + d0 + t] - mx) * inv;
    __syncthreads();
    const int rg = t >> 6, cg = t & 63;       // row-group, col-float4
    const float4v* qb = (const float4v*)(q + ((size_t)(b * DD + d0 + rg)) * HD) + cg;
    float4v a0 = {0,0,0,0}, a1 = {0,0,0,0};
    #pragma unroll 8
    for (int i = 0; i < 64; i += 2) {
        a0 += qb[(size_t)i * 256]       * wl[rg + i * 4];
        a1 += qb[(size_t)(i + 1) * 256] * wl[rg + (i + 1) * 4];
    }
    red[t] = a0 + a1;
    __syncthreads();
    if (t < 64) {
        float4v s = red[t] + red[t + 64] + red[t + 128] + red[t + 192];
        ((float4v*)part)[((size_t)(b * 8 + ch)) * 64 + t] = s;
    }
}

// ---------------- kernel 4: reduce partials ----------------
__global__ __launch_bounds__(64) void k_rout(const float* __restrict__ part,
                                             float* __restrict__ out) {
    int b = blockIdx.x, t = threadIdx.x;
    float4v s = {0,0,0,0};
    #pragma unroll
    for (int c = 0; c < 8; ++c) s += ((const float4v*)part)[((size_t)(b * 8 + c)) * 64 + t];
    ((float4v*)out)[b * 64 + t] = s;
}

extern "C" void kernel_launch(void* const* d_in, const int* in_sizes, int n_in,
                              void* d_out, int out_size, void* d_ws, size_t ws_size,
                              hipStream_t stream) {
    (void)in_sizes; (void)n_in; (void)out_size; (void)ws_size;
    const float* ctx = (const float*)d_in[0];
    const float* q   = (const float*)d_in[1];
    const float* hid = (const float*)d_in[2];
    const float* W1  = (const float*)d_in[3];
    const float* W2  = (const float*)d_in[4];
    const float* b2  = (const float*)d_in[5];
    const float* W3  = (const float*)d_in[6];
    const float* W4  = (const float*)d_in[7];
    // d_in[8] = b4: dropped (softmax shift-invariant)
    float* out = (float*)d_out;

    char* ws = (char*)d_ws;
    unsigned short* w1b = (unsigned short*)(ws);            // 131072 B
    float* g23    = (float*)(ws + 131072);                  //  65536 B
    float* scores = (float*)(ws + 196608);                  // 524288 B
    float* stats  = (float*)(ws + 720896);                  //    512 B
    float* part   = (float*)(ws + 721408);                  // 524288 B

    k_prep  <<<dim3(128), dim3(256), 0, stream>>>(W1, w1b, ctx, hid, W2, b2, W3, g23);
    k_scores<<<dim3(DD / 32, BB), dim3(256), 0, stream>>>(q, w1b, g23, W4, scores);
    k_stats <<<dim3(BB), dim3(256), 0, stream>>>(scores, stats);
    k_pout  <<<dim3(8, BB), dim3(256), 0, stream>>>(q, scores, stats, part);
    k_rout  <<<dim3(BB), dim3(64), 0, stream>>>(part, out);
}

// Round 4
// 82.610 us; speedup vs baseline: 1.5910x; 1.4753x over previous
//
#include <hip/hip_runtime.h>
#include <hip/hip_bf16.h>
#include <math.h>

#define HD 256
#define BB 64
#define DD 2048
#define NCHK 8          // d-chunks per batch (256 rows each)
#define NT 8            // 32-row tiles per chunk

// padded LDS row: 276 f32 words (1104 B); 16B-aligned rows for b128 reads.
#define ROWW 276
#define CHPR 69         // 16B chunks per padded row (69*16 = 1104)
#define NCH  35         // 1KB wave-chunks per 32-row tile

typedef __attribute__((ext_vector_type(8))) short  short8;
typedef __attribute__((ext_vector_type(4))) float  float4v;
typedef __attribute__((ext_vector_type(4))) unsigned short ushort4v;

__device__ inline unsigned short f2bf(float f) {
    unsigned u = __builtin_bit_cast(unsigned, f);
    u += 0x7FFFu + ((u >> 16) & 1u);   // RNE
    return (unsigned short)(u >> 16);
}

__device__ inline float fast_exp2(float x) {
    float r;
    asm("v_exp_f32 %0, %1" : "=v"(r) : "v"(x));
    return r;
}
__device__ inline float fast_expf(float x) { return fast_exp2(x * 1.4426950408889634f); }
__device__ inline float fast_tanh(float x) {
    float y = x * 2.8853900817779268f;          // 2x * log2(e)
    y = fminf(fmaxf(y, -30.f), 30.f);
    float t = fast_exp2(y);
    float r;
    asm("v_rcp_f32 %0, %1" : "=v"(r) : "v"(t + 1.f));
    return (t - 1.f) * r;
}

__device__ inline void load_lds16(const void* g, void* l) {
    __builtin_amdgcn_global_load_lds(
        (const __attribute__((address_space(1))) void*)g,
        (__attribute__((address_space(3))) void*)l, 16, 0, 0);
}

// issue 35 x 1KB gload_lds for one 32-row tile (f32, padded-row layout)
__device__ inline void stage_tile(const char* gtile, float* dst, int wave, int lane) {
    #pragma unroll
    for (int i = 0; i < 9; ++i) {
        int j = wave * 9 + i;
        if (j < NCH) {
            int x  = j * 64 + lane;            // 16B-chunk index in padded tile
            int r  = x / CHPR;
            int cb = x - r * CHPR;
            int rr = (r < 32) ? r : 0;         // pad -> dummy in-bounds addr
            int cc = (cb < 64) ? cb : 0;
            load_lds16(gtile + (size_t)rr * 1024 + cc * 16, (char*)dst + j * 1024);
        }
    }
}

// ---------------- kernel 0 (fused prep): W1 f32->bf16  AND  g23 ----------------
__global__ __launch_bounds__(256) void k_prep(const float* __restrict__ W1,
                                              unsigned short* __restrict__ w1b,
                                              const float* __restrict__ ctx,
                                              const float* __restrict__ hid,
                                              const float* __restrict__ W2,
                                              const float* __restrict__ b2,
                                              const float* __restrict__ W3,
                                              float* __restrict__ g23) {
    if (blockIdx.x < 64) {
        int i = blockIdx.x * 256 + threadIdx.x;
        float4v v = ((const float4v*)W1)[i];
        ushort4v o;
        o[0] = f2bf(v[0]); o[1] = f2bf(v[1]); o[2] = f2bf(v[2]); o[3] = f2bf(v[3]);
        ((ushort4v*)w1b)[i] = o;
    } else {
        int b = blockIdx.x - 64, t = threadIdx.x;
        __shared__ float c[HD], hh[HD];
        c[t]  = ctx[b * HD + t];
        hh[t] = hid[b * HD + t];
        __syncthreads();
        const float4v* w2 = (const float4v*)(W2 + (size_t)t * HD);
        const float4v* w3 = (const float4v*)(W3 + (size_t)t * HD);
        float acc = b2[t];
        #pragma unroll 8
        for (int k = 0; k < 64; ++k) {
            float4v a = w2[k], d = w3[k];
            int k4 = k * 4;
            acc += c[k4] * a[0] + c[k4 + 1] * a[1] + c[k4 + 2] * a[2] + c[k4 + 3] * a[3];
            acc += hh[k4] * d[0] + hh[k4 + 1] * d[1] + hh[k4 + 2] * d[2] + hh[k4 + 3] * d[3];
        }
        g23[b * HD + t] = acc;
    }
}

// ---------------- kernel 1 (fused main): flash-style scores+softmax+PV ----------------
// grid (8, 64): block owns (chunk, batch) = 256 d-rows; 8 tiles of 32, dbuf LDS.
// W1 fragments live in VGPRs; thread t accumulates O[h=t] in a register.
__global__ __launch_bounds__(256, 2) void k_fused(const float* __restrict__ q,
                                                  const unsigned short* __restrict__ w1b,
                                                  const float* __restrict__ g23,
                                                  const float* __restrict__ W4,
                                                  float* __restrict__ pstats,
                                                  float* __restrict__ pO) {
    __shared__ __attribute__((aligned(16))) float qs[2][NCH * 256];  // 2 x 35840 B
    __shared__ float sp[4 * 32];
    __shared__ float sp2[32];

    const int t = threadIdx.x;
    const int chunk = blockIdx.x, b = blockIdx.y;
    const int lane = t & 63, wave = t >> 6;
    const int l15 = lane & 15, lk = lane >> 4;
    const int hbase = wave * 64;

    const char* gchunk = (const char*)(q + ((size_t)(b * DD + chunk * 256)) * HD);

    // issue tile 0 loads first (start HBM fetch ASAP)
    stage_tile(gchunk, qs[0], wave, lane);

    // W1 fragments -> VGPRs (32 x short8 = 128 VGPR), L2-hot after k_prep
    short8 bfr[8][4];
    #pragma unroll
    for (int kb = 0; kb < 8; ++kb)
        #pragma unroll
        for (int nf = 0; nf < 4; ++nf)
            bfr[kb][nf] = *(const short8*)&w1b[(size_t)(hbase + nf * 16 + l15) * HD + kb * 32 + lk * 8];

    float g23v[4], w4v[4];
    #pragma unroll
    for (int nf = 0; nf < 4; ++nf) {
        int h = hbase + nf * 16 + l15;
        g23v[nf] = g23[b * HD + h];
        w4v[nf]  = W4[h];
    }

    float m = -1e30f, l = 0.f, Ot = 0.f;
    int cur = 0;

    for (int tt = 0; tt < NT; ++tt) {
        __syncthreads();                  // vmcnt drain: tile tt ready in qs[cur]
        const float* bufc = qs[cur];

        float4v acc[2][4];
        #pragma unroll
        for (int mf = 0; mf < 2; ++mf)
            #pragma unroll
            for (int nf = 0; nf < 4; ++nf)
                acc[mf][nf] = (float4v){0.f, 0.f, 0.f, 0.f};

        #pragma unroll
        for (int kb = 0; kb < 8; ++kb) {
            const int c0 = kb * 32 + lk * 8;
            short8 af[2];
            #pragma unroll
            for (int mf = 0; mf < 2; ++mf) {
                const float* p = &bufc[(mf * 16 + l15) * ROWW + c0];
                float4v lo = *(const float4v*)p;
                float4v hi = *(const float4v*)(p + 4);
                short8 a;
                a[0] = (short)f2bf(lo[0]); a[1] = (short)f2bf(lo[1]);
                a[2] = (short)f2bf(lo[2]); a[3] = (short)f2bf(lo[3]);
                a[4] = (short)f2bf(hi[0]); a[5] = (short)f2bf(hi[1]);
                a[6] = (short)f2bf(hi[2]); a[7] = (short)f2bf(hi[3]);
                af[mf] = a;
            }
            #pragma unroll
            for (int nf = 0; nf < 4; ++nf) {
                acc[0][nf] = __builtin_amdgcn_mfma_f32_16x16x32_bf16(af[0], bfr[kb][nf], acc[0][nf], 0, 0, 0);
                acc[1][nf] = __builtin_amdgcn_mfma_f32_16x16x32_bf16(af[1], bfr[kb][nf], acc[1][nf], 0, 0, 0);
            }
        }

        // tanh + W4 dot, reduce over 16 col-lanes -> per-wave partials
        #pragma unroll
        for (int mf = 0; mf < 2; ++mf)
            #pragma unroll
            for (int r = 0; r < 4; ++r) {
                float s = 0.f;
                #pragma unroll
                for (int nf = 0; nf < 4; ++nf)
                    s += fast_tanh(acc[mf][nf][r] + g23v[nf]) * w4v[nf];
                s += __shfl_xor(s, 1, 16);
                s += __shfl_xor(s, 2, 16);
                s += __shfl_xor(s, 4, 16);
                s += __shfl_xor(s, 8, 16);
                if (l15 == 0) sp[wave * 32 + mf * 16 + lk * 4 + r] = s;
            }
        __syncthreads();                  // vmcnt-free (nothing outstanding)
        if (t < 32) sp2[t] = sp[t] + sp[32 + t] + sp[64 + t] + sp[96 + t];
        __syncthreads();                  // vmcnt-free

        // issue next tile's loads NOW -> they fly under the online-update phase
        if (tt + 1 < NT)
            stage_tile(gchunk + (size_t)(tt + 1) * 32768, qs[cur ^ 1], wave, lane);

        // online softmax update + O accumulation (uniform m/l per thread)
        float tmax = sp2[0];
        #pragma unroll
        for (int d = 1; d < 32; ++d) tmax = fmaxf(tmax, sp2[d]);
        float mn  = fmaxf(m, tmax);
        float fct = fast_expf(m - mn);    // m=-1e30 -> 0 on first tile
        l *= fct; Ot *= fct;
        #pragma unroll 8
        for (int d = 0; d < 32; ++d) {
            float w = fast_expf(sp2[d] - mn);
            l += w;
            Ot += w * bufc[d * ROWW + t];   // conflict-free column read
        }
        m = mn;
        cur ^= 1;
    }

    pO[((size_t)(b * NCHK + chunk)) * HD + t] = Ot;
    if (t == 0) {
        pstats[(b * NCHK + chunk) * 2]     = m;
        pstats[(b * NCHK + chunk) * 2 + 1] = l;
    }
}

// ---------------- kernel 2: combine 8 chunk-partials per batch ----------------
__global__ __launch_bounds__(256) void k_comb(const float* __restrict__ pstats,
                                              const float* __restrict__ pO,
                                              float* __restrict__ out) {
    int b = blockIdx.x, t = threadIdx.x;
    float M = -1e30f;
    #pragma unroll
    for (int c = 0; c < NCHK; ++c) M = fmaxf(M, pstats[(b * NCHK + c) * 2]);
    float L = 0.f, s = 0.f;
    #pragma unroll
    for (int c = 0; c < NCHK; ++c) {
        float f = fast_expf(pstats[(b * NCHK + c) * 2] - M);
        L += f * pstats[(b * NCHK + c) * 2 + 1];
        s += f * pO[((size_t)(b * NCHK + c)) * HD + t];
    }
    out[b * HD + t] = s / L;
}

extern "C" void kernel_launch(void* const* d_in, const int* in_sizes, int n_in,
                              void* d_out, int out_size, void* d_ws, size_t ws_size,
                              hipStream_t stream) {
    (void)in_sizes; (void)n_in; (void)out_size; (void)ws_size;
    const float* ctx = (const float*)d_in[0];
    const float* q   = (const float*)d_in[1];
    const float* hid = (const float*)d_in[2];
    const float* W1  = (const float*)d_in[3];
    const float* W2  = (const float*)d_in[4];
    const float* b2  = (const float*)d_in[5];
    const float* W3  = (const float*)d_in[6];
    const float* W4  = (const float*)d_in[7];
    // d_in[8] = b4: dropped (softmax shift-invariant)
    float* out = (float*)d_out;

    char* ws = (char*)d_ws;
    unsigned short* w1b = (unsigned short*)(ws);            // 131072 B
    float* g23    = (float*)(ws + 131072);                  //  65536 B
    float* pstats = (float*)(ws + 196608);                  //   4096 B
    float* pO     = (float*)(ws + 200704);                  // 524288 B

    k_prep <<<dim3(128), dim3(256), 0, stream>>>(W1, w1b, ctx, hid, W2, b2, W3, g23);
    k_fused<<<dim3(NCHK, BB), dim3(256), 0, stream>>>(q, w1b, g23, W4, pstats, pO);
    k_comb <<<dim3(BB), dim3(256), 0, stream>>>(pstats, pO, out);
}